// Round 9
// baseline (650.196 us; speedup 1.0000x reference)
//
#include <hip/hip_runtime.h>
#include <hip/hip_fp16.h>

// ---------------------------------------------------------------------------
// Qwen2 attention block, MI355X (gfx950).
// B=2 S=2048 H=3584 NH=28 NKV=4 D=128  QS=3584 KVS=512 QKV=4608  M=B*S=4096
// fp16 MFMA (16x16x32) everywhere; fp32 accumulate; fp32 softmax/rope.
// R1-R11: see git history. Verified: XOR-swizzle kills bank conflicts;
//     GEMMs at 2-phase ceiling (~880 TF); never size LDS to exact capacity;
//     attn was LDS/softmax-machinery-bound, not HBM/VALU/conflict-bound.
// R12: WIN (668->618.5). TRUE T13 gate (per-lane pmax + __all, no shfl in
//     common case) + scale*log2e folded into Q at rope. attn 162 -> <153.
// R13: (a) GEMM2 retile 128x128 -> 128x224: 28 MFMA/iter vs 16 (+75% barrier
//     amortization), grid 16x32=512 at 3/CU (44KB LDS), all-resident. B-tile
//     stages 3 full 64-row chunks + half-chunk (tid<128, wave-uniform).
//     (b) Fuse 8 kernels -> 5: [cast + Wqkv^T] and [rope + vtrans + Wo^T]
//     (Wt dead after GEMM1; block-range branch, no divergent barriers).
//     gemm_wide + attn untouched (controls).
// ---------------------------------------------------------------------------

typedef _Float16 h8 __attribute__((ext_vector_type(8)));
typedef _Float16 h4 __attribute__((ext_vector_type(4)));
typedef float f4 __attribute__((ext_vector_type(4)));

__device__ __forceinline__ void gload_lds16(const void* g, void* l) {
  __builtin_amdgcn_global_load_lds(
      (const __attribute__((address_space(1))) void*)g,
      (__attribute__((address_space(3))) void*)l, 16, 0, 0);
}

// ---------------- fused: cast fp32->fp16 (hidden) + Wqkv^T transpose --------
// blocks [0,14336): cast; [14336, 14336+16128): transpose 3584x4608.
__global__ __launch_bounds__(256)
void fused_pre(const float4* __restrict__ hidden4, h4* __restrict__ hs,
               const float* __restrict__ Wqkv, _Float16* __restrict__ Wt) {
  const int bid = blockIdx.x, tid = threadIdx.x;
  if (bid < 14336) {
    int i = bid * 256 + tid;
    float4 v = hidden4[i];
    h4 o;
    o.x = (_Float16)v.x; o.y = (_Float16)v.y; o.z = (_Float16)v.z; o.w = (_Float16)v.w;
    hs[i] = o;
  } else {
    __shared__ float tile[32][33];
    const int t = bid - 14336;
    const int n0 = (t % 144) * 32, k0 = (t / 144) * 32;  // K=3584, N=4608
    const int tx = tid & 31, ty = tid >> 5;
#pragma unroll
    for (int i = ty; i < 32; i += 8)
      tile[i][tx] = Wqkv[(size_t)(k0 + i) * 4608 + n0 + tx];
    __syncthreads();
#pragma unroll
    for (int i = ty; i < 32; i += 8)
      Wt[(size_t)(n0 + i) * 3584 + k0 + tx] = (_Float16)tile[tx][i];
  }
}

// ---------------- fused: rope(Q pre-scaled, K) + V-transpose + Wo^T ---------
// blocks [0,4096): rope; [4096,6144): vtrans; [6144,6144+12544): Wo^T.
__global__ __launch_bounds__(256)
void fused_mid(const _Float16* __restrict__ qkv, const int* __restrict__ pos,
               _Float16* __restrict__ q, _Float16* __restrict__ k,
               _Float16* __restrict__ vt,
               const float* __restrict__ Wo, _Float16* __restrict__ Wt) {
  constexpr int S = 2048, NH = 28, NKV = 4, QKVW = 4608, QW = 3584, KVW = 512;
  const int bid = blockIdx.x, tid = threadIdx.x;
  if (bid < 4096) {
    // --- rope: Q scaled by head_dim^-0.5 * log2(e) ---
    constexpr float SCL = 0.12751743767f;  // 0.08838834765 * 1.44269504089
    const int token = bid;
    const int p = pos[token];
    __shared__ float cs[64], sn[64];
    if (tid < 64) {
      const float L = 0.31143075892695140f;  // log2(1e6)/64
      float inv = exp2f(-(float)tid * L);
      float ang = (float)p * inv;
      cs[tid] = cosf(ang);
      sn[tid] = sinf(ang);
    }
    __syncthreads();
    const _Float16* src = qkv + (size_t)token * QKVW;
    for (int i = tid; i < NH * 64; i += 256) {
      int hh = i >> 6, d = i & 63;
      float x1 = (float)src[hh * 128 + d];
      float x2 = (float)src[hh * 128 + d + 64];
      float c = cs[d], sv = sn[d];
      _Float16* dst = q + (size_t)token * QW + hh * 128 + d;
      dst[0]  = (_Float16)((x1 * c - x2 * sv) * SCL);
      dst[64] = (_Float16)((x2 * c + x1 * sv) * SCL);
    }
    for (int i = tid; i < NKV * 64; i += 256) {
      int hh = i >> 6, d = i & 63;
      float x1 = (float)src[QW + hh * 128 + d];
      float x2 = (float)src[QW + hh * 128 + d + 64];
      float c = cs[d], sv = sn[d];
      _Float16* dst = k + (size_t)token * KVW + hh * 128 + d;
      dst[0]  = (_Float16)(x1 * c - x2 * sv);
      dst[64] = (_Float16)(x2 * c + x1 * sv);
    }
  } else if (bid < 6144) {
    // --- vtrans: qkv V-cols -> Vt[b][kvh][d][S] ---
    __shared__ _Float16 t[32][33];
    const int vid = bid - 4096;
    const int b = vid >> 10, rem = vid & 1023;
    const int s0 = (rem & 63) * 32, d0 = (rem >> 6) * 32;
    const int tx = tid & 31, ty = tid >> 5;
#pragma unroll
    for (int i = ty; i < 32; i += 8)
      t[i][tx] = qkv[(size_t)(b * S + s0 + i) * QKVW + 4096 + d0 + tx];
    __syncthreads();
#pragma unroll
    for (int i = ty; i < 32; i += 8)
      vt[(size_t)(b * 512 + d0 + i) * S + s0 + tx] = t[tx][i];
  } else {
    // --- Wo^T: 3584x3584 fp32 -> fp16 (Wt region dead after GEMM1) ---
    __shared__ float tile[32][33];
    const int t = bid - 6144;
    const int n0 = (t % 112) * 32, k0 = (t / 112) * 32;
    const int tx = tid & 31, ty = tid >> 5;
#pragma unroll
    for (int i = ty; i < 32; i += 8)
      tile[i][tx] = Wo[(size_t)(k0 + i) * 3584 + n0 + tx];
    __syncthreads();
#pragma unroll
    for (int i = ty; i < 32; i += 8)
      Wt[(size_t)(n0 + i) * 3584 + k0 + tx] = (_Float16)tile[tx][i];
  }
}

// ---------------- GEMM1: 128x192 tile, grid-exact (24x32=768=3/CU) ----------
__global__ __launch_bounds__(256, 3)
void gemm_wide(const _Float16* __restrict__ A, const _Float16* __restrict__ Bt,
               const float* __restrict__ bias, _Float16* __restrict__ Cout,
               int M, int N, int K) {
  __shared__ _Float16 As[2][128 * 32];   // 2 x 8 KB
  __shared__ _Float16 Bs[2][192 * 32];   // 2 x 12 KB
  const int tid = threadIdx.x;
  const int m0 = blockIdx.y * 128, n0 = blockIdx.x * 192;
  const int lane = tid & 63, wave = tid >> 6;
  const int wm = (wave >> 1) * 64, wn = (wave & 1) * 96;
  const int r_ld = tid >> 2;          // staging row (0..63)
  const int c_swz = ((tid & 3) * 8) ^ (((r_ld >> 1) & 3) << 3);  // swizzled src col
  const int row_f = lane & 15, kg8 = (lane >> 4) * 8;
  const int kgx = kg8 ^ (((row_f >> 1) & 3) << 3);  // swizzled read col

  f4 acc[4][6] = {};
  const _Float16* Ag = A + (size_t)m0 * K + c_swz;
  const _Float16* Bg = Bt + (size_t)n0 * K + c_swz;

  auto stage = [&](int buf, int kk) {
#pragma unroll
    for (int i = 0; i < 2; ++i)
      gload_lds16(Ag + (size_t)(r_ld + i * 64) * K + kk,
                  &As[buf][0] + i * 2048 + tid * 8);
#pragma unroll
    for (int i = 0; i < 3; ++i)
      gload_lds16(Bg + (size_t)(r_ld + i * 64) * K + kk,
                  &Bs[buf][0] + i * 2048 + tid * 8);
  };

  // prologue
  stage(0, 0);
  asm volatile("s_waitcnt vmcnt(0)" ::: "memory");
  __builtin_amdgcn_s_barrier();
  __builtin_amdgcn_sched_barrier(0);

  int cur = 0;
  for (int kk = 0; kk < K; kk += 32) {
    if (kk + 32 < K) stage(cur ^ 1, kk + 32);
    __builtin_amdgcn_sched_barrier(0);

    h8 a_frag[4], b_frag[6];
#pragma unroll
    for (int t = 0; t < 4; ++t)
      a_frag[t] = *(const h8*)&As[cur][(wm + t * 16 + row_f) * 32 + kgx];
#pragma unroll
    for (int t = 0; t < 6; ++t)
      b_frag[t] = *(const h8*)&Bs[cur][(wn + t * 16 + row_f) * 32 + kgx];
    __builtin_amdgcn_s_setprio(1);
#pragma unroll
    for (int i = 0; i < 4; ++i)
#pragma unroll
      for (int j = 0; j < 6; ++j)
        acc[i][j] = __builtin_amdgcn_mfma_f32_16x16x32_f16(a_frag[i], b_frag[j], acc[i][j], 0, 0, 0);
    __builtin_amdgcn_s_setprio(0);

    __builtin_amdgcn_sched_barrier(0);
    asm volatile("s_waitcnt vmcnt(0)" ::: "memory");
    __builtin_amdgcn_s_barrier();
    __builtin_amdgcn_sched_barrier(0);
    cur ^= 1;
  }

  // epilogue: C/D layout col = lane&15, row = (lane>>4)*4 + r
  const int col_f = lane & 15, rgrp = (lane >> 4) * 4;
#pragma unroll
  for (int i = 0; i < 4; ++i) {
#pragma unroll
    for (int j = 0; j < 6; ++j) {
      const int col = n0 + wn + j * 16 + col_f;
      const float bv = bias[col];
#pragma unroll
      for (int r = 0; r < 4; ++r) {
        const int row = m0 + wm + i * 16 + rgrp + r;
        Cout[(size_t)row * N + col] = (_Float16)(acc[i][j][r] + bv);
      }
    }
  }
}

// ---------------- GEMM2: 128x224 tile, fp32 out, no bias --------------------
// grid (16,32)=512 blocks at 3/CU (LDS 44KB*3=132KB) — all-resident, no tail.
// 28 MFMA/iter (vs 16 at 128x128): barrier drain amortized 75% better.
// B-tile 224 rows: 3 full 64-row chunks + half chunk (tid<128, wave-uniform).
__global__ __launch_bounds__(256, 3)
void gemm2(const _Float16* __restrict__ A, const _Float16* __restrict__ Bt,
           float* __restrict__ Cout, int M, int N, int K) {
  __shared__ _Float16 As[2][128 * 32];   // 2 x 8 KB
  __shared__ _Float16 Bs[2][224 * 32];   // 2 x 14 KB
  const int tid = threadIdx.x;
  const int m0 = blockIdx.y * 128, n0 = blockIdx.x * 224;
  const int lane = tid & 63, wave = tid >> 6;
  const int wm = (wave >> 1) * 64, wn = (wave & 1) * 112;
  const int r_ld = tid >> 2;          // staging row (0..63)
  const int c_swz = ((tid & 3) * 8) ^ (((r_ld >> 1) & 3) << 3);
  const int row_f = lane & 15, kg8 = (lane >> 4) * 8;
  const int kgx = kg8 ^ (((row_f >> 1) & 3) << 3);

  f4 acc[4][7] = {};
  const _Float16* Ag = A + (size_t)m0 * K + c_swz;
  const _Float16* Bg = Bt + (size_t)n0 * K + c_swz;

  auto stage = [&](int buf, int kk) {
#pragma unroll
    for (int i = 0; i < 2; ++i)
      gload_lds16(Ag + (size_t)(r_ld + i * 64) * K + kk,
                  &As[buf][0] + i * 2048 + tid * 8);
#pragma unroll
    for (int i = 0; i < 3; ++i)
      gload_lds16(Bg + (size_t)(r_ld + i * 64) * K + kk,
                  &Bs[buf][0] + i * 2048 + tid * 8);
    if (tid < 128)   // rows 192..223 (half chunk; 192%8==0 keeps swizzle phase)
      gload_lds16(Bg + (size_t)(r_ld + 192) * K + kk,
                  &Bs[buf][0] + 6144 + tid * 8);
  };

  stage(0, 0);
  asm volatile("s_waitcnt vmcnt(0)" ::: "memory");
  __builtin_amdgcn_s_barrier();
  __builtin_amdgcn_sched_barrier(0);

  int cur = 0;
  for (int kk = 0; kk < K; kk += 32) {
    if (kk + 32 < K) stage(cur ^ 1, kk + 32);
    __builtin_amdgcn_sched_barrier(0);

    h8 a_frag[4], b_frag[7];
#pragma unroll
    for (int t = 0; t < 4; ++t)
      a_frag[t] = *(const h8*)&As[cur][(wm + t * 16 + row_f) * 32 + kgx];
#pragma unroll
    for (int t = 0; t < 7; ++t)
      b_frag[t] = *(const h8*)&Bs[cur][(wn + t * 16 + row_f) * 32 + kgx];
    __builtin_amdgcn_s_setprio(1);
#pragma unroll
    for (int i = 0; i < 4; ++i)
#pragma unroll
      for (int j = 0; j < 7; ++j)
        acc[i][j] = __builtin_amdgcn_mfma_f32_16x16x32_f16(a_frag[i], b_frag[j], acc[i][j], 0, 0, 0);
    __builtin_amdgcn_s_setprio(0);

    __builtin_amdgcn_sched_barrier(0);
    asm volatile("s_waitcnt vmcnt(0)" ::: "memory");
    __builtin_amdgcn_s_barrier();
    __builtin_amdgcn_sched_barrier(0);
    cur ^= 1;
  }

  // epilogue: C/D layout col = lane&15, row = (lane>>4)*4 + r
  const int col_f = lane & 15, rgrp = (lane >> 4) * 4;
#pragma unroll
  for (int i = 0; i < 4; ++i) {
#pragma unroll
    for (int j = 0; j < 7; ++j) {
      const int col = n0 + wn + j * 16 + col_f;
#pragma unroll
      for (int r = 0; r < 4; ++r) {
        const int row = m0 + wm + i * 16 + rgrp + r;
        Cout[(size_t)row * N + col] = acc[i][j][r];
      }
    }
  }
}

// ---------------- flash attention (causal, GQA, KV shared across 7 heads) ----
// grid 512 blocks x 448 threads. Block = (32 q-rows) x (7 heads of one kvh).
// Each wave: two 16-row q groups; kf/vf b128 reads feed 2 MFMAs each.
// Single-buffered K/V; stageV(kt) before QK^T, E=vmcnt+barrier, stageK(kt+1)
// before PV, G=vmcnt+barrier. XOR-swizzled K/V slots.
// R12 softmax: TRUE T13 — per-lane partial max + __all gate (no DS ops);
// shfl-max chain + rescale only on the rare exact path. Scores arrive
// pre-scaled (exp2 domain). l_i per-lane partials, epilogue-reduced.
// launch_bounds (448,2): VGPR cap 256 — DO NOT tighten.
__global__ __launch_bounds__(448, 2)
void attn_kernel(const _Float16* __restrict__ Q,   // [B*S][NH*128] rope'd, pre-scaled
                 const _Float16* __restrict__ Kh,  // [B*S][NKV*128] rope'd
                 const _Float16* __restrict__ Vt,  // [B][NKV][128][S]
                 _Float16* __restrict__ Oh) {      // [B*S][NH*128]
  constexpr int S = 2048, D = 128, NH = 28, NKV = 4;
  const int id = blockIdx.x;
  const int qt = 63 - (id >> 3);           // 32-row q tile, longest first
  const int b = (id >> 2) & 1, kvh = id & 3;
  const int tid = threadIdx.x, lane = tid & 63, wave = tid >> 6;  // wave 0..6
  const int h = kvh * 7 + wave;            // this wave's query head
  const int q0 = qt * 32;
  const int row_f = lane & 15, kg = lane >> 4, kg8 = (lane >> 4) * 8;
  const int kgx = kg8 ^ (((row_f >> 1) & 3) << 3);  // swizzled fragment column

  __shared__ _Float16 Ks[4][64][32];   // [d_chunk][key][32 d] = 16 KB
  __shared__ _Float16 Vs[2][128][32];  // [key_chunk][d][32 keys] = 16 KB
  __shared__ _Float16 Ps[7][32][72];   // per-wave P^T scratch (2 groups)

  // load Q fragments for both 16-row groups (A-operand layout)
  h8 qf0[4], qf1[4];
  {
    const _Float16* qr0 = Q + ((size_t)(b * S + q0 + row_f) * NH + h) * D;
    const _Float16* qr1 = Q + ((size_t)(b * S + q0 + 16 + row_f) * NH + h) * D;
#pragma unroll
    for (int ks = 0; ks < 4; ++ks) {
      qf0[ks] = *(const h8*)(qr0 + ks * 32 + kg8);
      qf1[ks] = *(const h8*)(qr1 + ks * 32 + kg8);
    }
  }
  f4 o_acc0[8] = {}, o_acc1[8] = {};
  float m_i0[4] = {-1e30f, -1e30f, -1e30f, -1e30f};
  float m_i1[4] = {-1e30f, -1e30f, -1e30f, -1e30f};
  float l_i0[4] = {0.f, 0.f, 0.f, 0.f};   // per-lane partials
  float l_i1[4] = {0.f, 0.f, 0.f, 0.f};

  const _Float16* kbase = Kh + ((size_t)(b * S) * NKV + kvh) * D;
  const _Float16* vbase = Vt + ((size_t)(b * NKV + kvh) * D) * S;

  const int kt_max = (q0 + 31) >> 6;  // last 64-key tile (diagonal)

  auto stageK = [&](int kt) {
#pragma unroll
    for (int is = 0; is < 4; ++is) {
      int off = (is * 256 + tid) * 8;
      int chunk = off >> 11;
      int key = (off >> 5) & 63;
      int dl = (off & 31) ^ (((key >> 1) & 3) << 3);
      gload_lds16(kbase + (size_t)(kt * 64 + key) * (NKV * D) + chunk * 32 + dl,
                  &Ks[0][0][0] + off);
    }
  };
  auto stageV = [&](int kt) {
#pragma unroll
    for (int is = 0; is < 4; ++is) {
      int off = (is * 256 + tid) * 8;
      int chunk = off >> 12;
      int d = (off >> 5) & 127;
      int kl = (off & 31) ^ (((d >> 1) & 3) << 3);
      gload_lds16(vbase + (size_t)d * S + kt * 64 + chunk * 32 + kl,
                  &Vs[0][0][0] + off);
    }
  };

  // softmax for one 16-row group; T13 per-lane gate (no DS in common case)
  auto softmax_g = [&](f4* s_acc, float* m_i, float* l_i, f4* o_acc,
                       int goff, bool diag, int kt) {
    float sv[4][4];
#pragma unroll
    for (int nt = 0; nt < 4; ++nt) {
#pragma unroll
      for (int r = 0; r < 4; ++r) {
        float v = s_acc[nt][r];   // already scaled (rope pre-scale)
        if (diag) {
          int key = kt * 64 + nt * 16 + row_f;
          int row = q0 + goff + kg * 4 + r;
          if (key > row) v = -1e30f;
        }
        sv[nt][r] = v;
      }
    }
    float pmax[4];
    bool ok = true;
#pragma unroll
    for (int r = 0; r < 4; ++r) {
      pmax[r] = fmaxf(fmaxf(sv[0][r], sv[1][r]), fmaxf(sv[2][r], sv[3][r]));
      ok = ok && (pmax[r] <= m_i[r] + 8.0f);
    }
    if (!__all(ok)) {
#pragma unroll
      for (int r = 0; r < 4; ++r) {
        float mx = pmax[r];
#pragma unroll
        for (int off = 8; off >= 1; off >>= 1)
          mx = fmaxf(mx, __shfl_xor(mx, off, 64));
        float mn = fmaxf(m_i[r], mx);
        float alpha = exp2f(m_i[r] - mn);
        m_i[r] = mn;
        l_i[r] *= alpha;
#pragma unroll
        for (int dt = 0; dt < 8; ++dt) o_acc[dt][r] *= alpha;
      }
    }
#pragma unroll
    for (int r = 0; r < 4; ++r) {
      float ls = 0.f;
#pragma unroll
      for (int nt = 0; nt < 4; ++nt) {
        float p = exp2f(sv[nt][r] - m_i[r]);   // bounded by 2^8 when gated
        sv[nt][r] = p;
        ls += p;
      }
      l_i[r] += ls;
    }
#pragma unroll
    for (int nt = 0; nt < 4; ++nt)
#pragma unroll
      for (int r = 0; r < 4; ++r)
        Ps[wave][goff + kg * 4 + r][nt * 16 + row_f] = (_Float16)sv[nt][r];
  };

  // prologue: K(0) resident before first QK^T
  if (tid < 256) stageK(0);
  asm volatile("s_waitcnt vmcnt(0)" ::: "memory");
  __builtin_amdgcn_s_barrier();
  __builtin_amdgcn_sched_barrier(0);

  for (int kt = 0; kt <= kt_max; ++kt) {
    if (tid < 256) stageV(kt);
    __builtin_amdgcn_sched_barrier(0);

    // S = Q K^T  (32 q x 64 keys per wave; each kf feeds 2 MFMAs)
    f4 s0[4] = {}, s1[4] = {};
    __builtin_amdgcn_s_setprio(1);
#pragma unroll
    for (int ks = 0; ks < 4; ++ks) {
#pragma unroll
      for (int nt = 0; nt < 4; ++nt) {
        h8 kf = *(const h8*)&Ks[ks][nt * 16 + row_f][kgx];
        s0[nt] = __builtin_amdgcn_mfma_f32_16x16x32_f16(qf0[ks], kf, s0[nt], 0, 0, 0);
        s1[nt] = __builtin_amdgcn_mfma_f32_16x16x32_f16(qf1[ks], kf, s1[nt], 0, 0, 0);
      }
    }
    __builtin_amdgcn_s_setprio(0);

    const bool diag = (kt == kt_max);
    softmax_g(s0, m_i0, l_i0, o_acc0, 0, diag, kt);
    softmax_g(s1, m_i1, l_i1, o_acc1, 16, diag, kt);

    // E: V(kt) landed; all waves done reading Ks -> safe to overwrite.
    __builtin_amdgcn_sched_barrier(0);
    asm volatile("s_waitcnt vmcnt(0)" ::: "memory");
    __builtin_amdgcn_s_barrier();
    __builtin_amdgcn_sched_barrier(0);

    if (kt < kt_max && tid < 256) stageK(kt + 1);
    __builtin_amdgcn_sched_barrier(0);

    // O += P V  (each vf feeds 2 MFMAs)
    __builtin_amdgcn_s_setprio(1);
#pragma unroll
    for (int kv = 0; kv < 2; ++kv) {
      h8 pf0 = *(const h8*)&Ps[wave][row_f][kv * 32 + kg8];
      h8 pf1 = *(const h8*)&Ps[wave][16 + row_f][kv * 32 + kg8];
#pragma unroll
      for (int dt = 0; dt < 8; ++dt) {
        h8 vf = *(const h8*)&Vs[kv][dt * 16 + row_f][kgx];
        o_acc0[dt] = __builtin_amdgcn_mfma_f32_16x16x32_f16(pf0, vf, o_acc0[dt], 0, 0, 0);
        o_acc1[dt] = __builtin_amdgcn_mfma_f32_16x16x32_f16(pf1, vf, o_acc1[dt], 0, 0, 0);
      }
    }
    __builtin_amdgcn_s_setprio(0);

    // G: K(kt+1) landed; all waves done reading Vs -> next stageV safe.
    __builtin_amdgcn_sched_barrier(0);
    asm volatile("s_waitcnt vmcnt(0)" ::: "memory");
    __builtin_amdgcn_s_barrier();
    __builtin_amdgcn_sched_barrier(0);
  }

  // epilogue: reduce l across the 16-lane row group, O /= l, store
  float inv_l0[4], inv_l1[4];
#pragma unroll
  for (int r = 0; r < 4; ++r) {
    float ls0 = l_i0[r], ls1 = l_i1[r];
#pragma unroll
    for (int off = 8; off >= 1; off >>= 1) {
      ls0 += __shfl_xor(ls0, off, 64);
      ls1 += __shfl_xor(ls1, off, 64);
    }
    inv_l0[r] = 1.0f / ls0;
    inv_l1[r] = 1.0f / ls1;
  }
#pragma unroll
  for (int dt = 0; dt < 8; ++dt) {
#pragma unroll
    for (int r = 0; r < 4; ++r) {
      const int tok0 = b * S + q0 + kg * 4 + r;
      const int d = dt * 16 + row_f;
      Oh[((size_t)tok0 * NH + h) * D + d] = (_Float16)(o_acc0[dt][r] * inv_l0[r]);
      Oh[((size_t)(tok0 + 16) * NH + h) * D + d] = (_Float16)(o_acc1[dt][r] * inv_l1[r]);
    }
  }
}

// ---------------------------------------------------------------------------
extern "C" void kernel_launch(void* const* d_in, const int* in_sizes, int n_in,
                              void* d_out, int out_size, void* d_ws, size_t ws_size,
                              hipStream_t stream) {
  const float* hidden    = (const float*)d_in[0];
  const int*   positions = (const int*)d_in[1];
  const float* Wqkv      = (const float*)d_in[2];
  const float* bqkv      = (const float*)d_in[3];
  const float* Wo        = (const float*)d_in[4];
  float* out = (float*)d_out;

  // workspace layout (bytes)
  char* ws = (char*)d_ws;
  _Float16* hs_h  = (_Float16*)(ws);              // 4096x3584 fp16 (later reused as attn out)
  _Float16* Wt    = (_Float16*)(ws + 29360128);   // max 4608x3584 fp16 (Wqkv^T then Wo^T)
  _Float16* qkv_h = (_Float16*)(ws + 62390272);   // 4096x4608 fp16
  _Float16* q_h   = (_Float16*)(ws + 100139008);  // 4096x3584 fp16
  _Float16* k_h   = (_Float16*)(ws + 129499136);  // 4096x512 fp16
  _Float16* vt_h  = (_Float16*)(ws + 133693440);  // 2x4x128x2048 fp16
  // total 137,887,744 bytes

  // 1. [fused] hidden fp32->fp16 + Wqkv^T  (14336 + 144*112 = 30464 blocks)
  fused_pre<<<30464, 256, 0, stream>>>((const float4*)hidden, (h4*)hs_h, Wqkv, Wt);
  // 2. qkv = hidden @ Wqkv + b   (fp16 out) — 128x192 tiles, grid-exact 768
  gemm_wide<<<dim3(24, 32), 256, 0, stream>>>(hs_h, Wt, bqkv, qkv_h, 4096, 4608, 3584);
  // 3. [fused] rope(Q pre-scaled,K) + vtrans + Wo^T (4096+2048+12544 blocks)
  fused_mid<<<18688, 256, 0, stream>>>(qkv_h, positions, q_h, k_h, vt_h, Wo, Wt);
  // 4. flash attention -> attn fp16 (into hs_h, dead after GEMM1)
  attn_kernel<<<512, 448, 0, stream>>>(q_h, k_h, vt_h, hs_h);
  // 5. out = attn @ Wo   (fp32 out) — 128x224 tiles, 512 blocks all-resident
  gemm2<<<dim3(16, 32), 256, 0, stream>>>(hs_h, Wt, out, 4096, 3584, 3584);
}

// Round 10
// 617.025 us; speedup vs baseline: 1.0538x; 1.0538x over previous
//
#include <hip/hip_runtime.h>
#include <hip/hip_fp16.h>

// ---------------------------------------------------------------------------
// Qwen2 attention block, MI355X (gfx950).
// B=2 S=2048 H=3584 NH=28 NKV=4 D=128  QS=3584 KVS=512 QKV=4608  M=B*S=4096
// fp16 MFMA (16x16x32) everywhere; fp32 accumulate; fp32 softmax/rope.
// R1-R12: see git history. Verified: XOR-swizzle kills bank conflicts;
//     GEMMs at 2-phase ceiling (~880 TF at >=3 blocks/CU); never size LDS to
//     exact capacity; attn softmax machinery was the plateau (T13 gate fixed).
// R12: WIN (668->618.5). T13 per-lane gate + scale folded into Q.
// R13: MIXED (650). Fusions (8->5 kernels) saved ~18us BUT gemm2 128x224
//     REGRESSED 50us: grid 16x32=512 = 2 blocks/CU only (occ 22%, MfmaUtil
//     24) — per-iter barrier drain needs >=3 resident blocks of inter-block
//     TLP. LESSON (R5 family): residency term dominates per-iter
//     amortization. N/224=16 forces the small grid -> retile is dead.
// R14: revert GEMM2 to the proven 128x128 gemm_kernel (896 blocks = 3.5/CU,
//     <=153us in R8-R12); keep both fusions. Nothing else changed.
// ---------------------------------------------------------------------------

typedef _Float16 h8 __attribute__((ext_vector_type(8)));
typedef _Float16 h4 __attribute__((ext_vector_type(4)));
typedef float f4 __attribute__((ext_vector_type(4)));

__device__ __forceinline__ void gload_lds16(const void* g, void* l) {
  __builtin_amdgcn_global_load_lds(
      (const __attribute__((address_space(1))) void*)g,
      (__attribute__((address_space(3))) void*)l, 16, 0, 0);
}

// ---------------- fused: cast fp32->fp16 (hidden) + Wqkv^T transpose --------
// blocks [0,14336): cast; [14336, 14336+16128): transpose 3584x4608.
__global__ __launch_bounds__(256)
void fused_pre(const float4* __restrict__ hidden4, h4* __restrict__ hs,
               const float* __restrict__ Wqkv, _Float16* __restrict__ Wt) {
  const int bid = blockIdx.x, tid = threadIdx.x;
  if (bid < 14336) {
    int i = bid * 256 + tid;
    float4 v = hidden4[i];
    h4 o;
    o.x = (_Float16)v.x; o.y = (_Float16)v.y; o.z = (_Float16)v.z; o.w = (_Float16)v.w;
    hs[i] = o;
  } else {
    __shared__ float tile[32][33];
    const int t = bid - 14336;
    const int n0 = (t % 144) * 32, k0 = (t / 144) * 32;  // K=3584, N=4608
    const int tx = tid & 31, ty = tid >> 5;
#pragma unroll
    for (int i = ty; i < 32; i += 8)
      tile[i][tx] = Wqkv[(size_t)(k0 + i) * 4608 + n0 + tx];
    __syncthreads();
#pragma unroll
    for (int i = ty; i < 32; i += 8)
      Wt[(size_t)(n0 + i) * 3584 + k0 + tx] = (_Float16)tile[tx][i];
  }
}

// ---------------- fused: rope(Q pre-scaled, K) + V-transpose + Wo^T ---------
// blocks [0,4096): rope; [4096,6144): vtrans; [6144,6144+12544): Wo^T.
__global__ __launch_bounds__(256)
void fused_mid(const _Float16* __restrict__ qkv, const int* __restrict__ pos,
               _Float16* __restrict__ q, _Float16* __restrict__ k,
               _Float16* __restrict__ vt,
               const float* __restrict__ Wo, _Float16* __restrict__ Wt) {
  constexpr int S = 2048, NH = 28, NKV = 4, QKVW = 4608, QW = 3584, KVW = 512;
  const int bid = blockIdx.x, tid = threadIdx.x;
  if (bid < 4096) {
    // --- rope: Q scaled by head_dim^-0.5 * log2(e) ---
    constexpr float SCL = 0.12751743767f;  // 0.08838834765 * 1.44269504089
    const int token = bid;
    const int p = pos[token];
    __shared__ float cs[64], sn[64];
    if (tid < 64) {
      const float L = 0.31143075892695140f;  // log2(1e6)/64
      float inv = exp2f(-(float)tid * L);
      float ang = (float)p * inv;
      cs[tid] = cosf(ang);
      sn[tid] = sinf(ang);
    }
    __syncthreads();
    const _Float16* src = qkv + (size_t)token * QKVW;
    for (int i = tid; i < NH * 64; i += 256) {
      int hh = i >> 6, d = i & 63;
      float x1 = (float)src[hh * 128 + d];
      float x2 = (float)src[hh * 128 + d + 64];
      float c = cs[d], sv = sn[d];
      _Float16* dst = q + (size_t)token * QW + hh * 128 + d;
      dst[0]  = (_Float16)((x1 * c - x2 * sv) * SCL);
      dst[64] = (_Float16)((x2 * c + x1 * sv) * SCL);
    }
    for (int i = tid; i < NKV * 64; i += 256) {
      int hh = i >> 6, d = i & 63;
      float x1 = (float)src[QW + hh * 128 + d];
      float x2 = (float)src[QW + hh * 128 + d + 64];
      float c = cs[d], sv = sn[d];
      _Float16* dst = k + (size_t)token * KVW + hh * 128 + d;
      dst[0]  = (_Float16)(x1 * c - x2 * sv);
      dst[64] = (_Float16)(x2 * c + x1 * sv);
    }
  } else if (bid < 6144) {
    // --- vtrans: qkv V-cols -> Vt[b][kvh][d][S] ---
    __shared__ _Float16 t[32][33];
    const int vid = bid - 4096;
    const int b = vid >> 10, rem = vid & 1023;
    const int s0 = (rem & 63) * 32, d0 = (rem >> 6) * 32;
    const int tx = tid & 31, ty = tid >> 5;
#pragma unroll
    for (int i = ty; i < 32; i += 8)
      t[i][tx] = qkv[(size_t)(b * S + s0 + i) * QKVW + 4096 + d0 + tx];
    __syncthreads();
#pragma unroll
    for (int i = ty; i < 32; i += 8)
      vt[(size_t)(b * 512 + d0 + i) * S + s0 + tx] = t[tx][i];
  } else {
    // --- Wo^T: 3584x3584 fp32 -> fp16 (Wt region dead after GEMM1) ---
    __shared__ float tile[32][33];
    const int t = bid - 6144;
    const int n0 = (t % 112) * 32, k0 = (t / 112) * 32;
    const int tx = tid & 31, ty = tid >> 5;
#pragma unroll
    for (int i = ty; i < 32; i += 8)
      tile[i][tx] = Wo[(size_t)(k0 + i) * 3584 + n0 + tx];
    __syncthreads();
#pragma unroll
    for (int i = ty; i < 32; i += 8)
      Wt[(size_t)(n0 + i) * 3584 + k0 + tx] = (_Float16)tile[tx][i];
  }
}

// ---------------- GEMM1: 128x192 tile, grid-exact (24x32=768=3/CU) ----------
__global__ __launch_bounds__(256, 3)
void gemm_wide(const _Float16* __restrict__ A, const _Float16* __restrict__ Bt,
               const float* __restrict__ bias, _Float16* __restrict__ Cout,
               int M, int N, int K) {
  __shared__ _Float16 As[2][128 * 32];   // 2 x 8 KB
  __shared__ _Float16 Bs[2][192 * 32];   // 2 x 12 KB
  const int tid = threadIdx.x;
  const int m0 = blockIdx.y * 128, n0 = blockIdx.x * 192;
  const int lane = tid & 63, wave = tid >> 6;
  const int wm = (wave >> 1) * 64, wn = (wave & 1) * 96;
  const int r_ld = tid >> 2;          // staging row (0..63)
  const int c_swz = ((tid & 3) * 8) ^ (((r_ld >> 1) & 3) << 3);  // swizzled src col
  const int row_f = lane & 15, kg8 = (lane >> 4) * 8;
  const int kgx = kg8 ^ (((row_f >> 1) & 3) << 3);  // swizzled read col

  f4 acc[4][6] = {};
  const _Float16* Ag = A + (size_t)m0 * K + c_swz;
  const _Float16* Bg = Bt + (size_t)n0 * K + c_swz;

  auto stage = [&](int buf, int kk) {
#pragma unroll
    for (int i = 0; i < 2; ++i)
      gload_lds16(Ag + (size_t)(r_ld + i * 64) * K + kk,
                  &As[buf][0] + i * 2048 + tid * 8);
#pragma unroll
    for (int i = 0; i < 3; ++i)
      gload_lds16(Bg + (size_t)(r_ld + i * 64) * K + kk,
                  &Bs[buf][0] + i * 2048 + tid * 8);
  };

  // prologue
  stage(0, 0);
  asm volatile("s_waitcnt vmcnt(0)" ::: "memory");
  __builtin_amdgcn_s_barrier();
  __builtin_amdgcn_sched_barrier(0);

  int cur = 0;
  for (int kk = 0; kk < K; kk += 32) {
    if (kk + 32 < K) stage(cur ^ 1, kk + 32);
    __builtin_amdgcn_sched_barrier(0);

    h8 a_frag[4], b_frag[6];
#pragma unroll
    for (int t = 0; t < 4; ++t)
      a_frag[t] = *(const h8*)&As[cur][(wm + t * 16 + row_f) * 32 + kgx];
#pragma unroll
    for (int t = 0; t < 6; ++t)
      b_frag[t] = *(const h8*)&Bs[cur][(wn + t * 16 + row_f) * 32 + kgx];
    __builtin_amdgcn_s_setprio(1);
#pragma unroll
    for (int i = 0; i < 4; ++i)
#pragma unroll
      for (int j = 0; j < 6; ++j)
        acc[i][j] = __builtin_amdgcn_mfma_f32_16x16x32_f16(a_frag[i], b_frag[j], acc[i][j], 0, 0, 0);
    __builtin_amdgcn_s_setprio(0);

    __builtin_amdgcn_sched_barrier(0);
    asm volatile("s_waitcnt vmcnt(0)" ::: "memory");
    __builtin_amdgcn_s_barrier();
    __builtin_amdgcn_sched_barrier(0);
    cur ^= 1;
  }

  // epilogue: C/D layout col = lane&15, row = (lane>>4)*4 + r
  const int col_f = lane & 15, rgrp = (lane >> 4) * 4;
#pragma unroll
  for (int i = 0; i < 4; ++i) {
#pragma unroll
    for (int j = 0; j < 6; ++j) {
      const int col = n0 + wn + j * 16 + col_f;
      const float bv = bias[col];
#pragma unroll
      for (int r = 0; r < 4; ++r) {
        const int row = m0 + wm + i * 16 + rgrp + r;
        Cout[(size_t)row * N + col] = (_Float16)(acc[i][j][r] + bv);
      }
    }
  }
}

// ---------------- GEMM2: C[M][N] = A[M][K] * Bt[N][K]^T, fp32 out -----------
// 128x128 block tile, BK=32 double-buffered (2x16KB = 32KB), 896 blocks =
// 3.5 blocks/CU (R13 lesson: >=3 resident blocks needed to hide the per-iter
// barrier drain; 128x224's 512-block grid = 2/CU regressed 50us).
__global__ __launch_bounds__(256, 4)
void gemm_kernel(const _Float16* __restrict__ A, const _Float16* __restrict__ Bt,
                 float* __restrict__ Cout, int M, int N, int K) {
  __shared__ _Float16 As[2][128 * 32];
  __shared__ _Float16 Bs[2][128 * 32];
  const int tid = threadIdx.x;
  const int m0 = blockIdx.y * 128, n0 = blockIdx.x * 128;
  const int lane = tid & 63, wave = tid >> 6;
  const int wm = (wave >> 1) * 64, wn = (wave & 1) * 64;
  const int r_ld = tid >> 2;          // staging row (0..63)
  const int c_swz = ((tid & 3) * 8) ^ (((r_ld >> 1) & 3) << 3);
  const int row_f = lane & 15, kg8 = (lane >> 4) * 8;
  const int kgx = kg8 ^ (((row_f >> 1) & 3) << 3);

  f4 acc[4][4] = {};
  const _Float16* Ag = A + (size_t)m0 * K + c_swz;
  const _Float16* Bg = Bt + (size_t)n0 * K + c_swz;

  auto stage = [&](int buf, int kk) {
#pragma unroll
    for (int i = 0; i < 2; ++i) {
      gload_lds16(Ag + (size_t)(r_ld + i * 64) * K + kk,
                  &As[buf][0] + i * 2048 + tid * 8);
      gload_lds16(Bg + (size_t)(r_ld + i * 64) * K + kk,
                  &Bs[buf][0] + i * 2048 + tid * 8);
    }
  };

  stage(0, 0);
  asm volatile("s_waitcnt vmcnt(0)" ::: "memory");
  __builtin_amdgcn_s_barrier();
  __builtin_amdgcn_sched_barrier(0);

  int cur = 0;
  for (int kk = 0; kk < K; kk += 32) {
    if (kk + 32 < K) stage(cur ^ 1, kk + 32);
    __builtin_amdgcn_sched_barrier(0);

    h8 a_frag[4], b_frag[4];
#pragma unroll
    for (int t = 0; t < 4; ++t)
      a_frag[t] = *(const h8*)&As[cur][(wm + t * 16 + row_f) * 32 + kgx];
#pragma unroll
    for (int t = 0; t < 4; ++t)
      b_frag[t] = *(const h8*)&Bs[cur][(wn + t * 16 + row_f) * 32 + kgx];
    __builtin_amdgcn_s_setprio(1);
#pragma unroll
    for (int i = 0; i < 4; ++i)
#pragma unroll
      for (int j = 0; j < 4; ++j)
        acc[i][j] = __builtin_amdgcn_mfma_f32_16x16x32_f16(a_frag[i], b_frag[j], acc[i][j], 0, 0, 0);
    __builtin_amdgcn_s_setprio(0);

    __builtin_amdgcn_sched_barrier(0);
    asm volatile("s_waitcnt vmcnt(0)" ::: "memory");
    __builtin_amdgcn_s_barrier();
    __builtin_amdgcn_sched_barrier(0);
    cur ^= 1;
  }

  // epilogue: C/D layout col = lane&15, row = (lane>>4)*4 + r
  const int col_f = lane & 15, rgrp = (lane >> 4) * 4;
#pragma unroll
  for (int i = 0; i < 4; ++i) {
#pragma unroll
    for (int j = 0; j < 4; ++j) {
      const int col = n0 + wn + j * 16 + col_f;
#pragma unroll
      for (int r = 0; r < 4; ++r) {
        const int row = m0 + wm + i * 16 + rgrp + r;
        Cout[(size_t)row * N + col] = acc[i][j][r];
      }
    }
  }
}

// ---------------- flash attention (causal, GQA, KV shared across 7 heads) ----
// grid 512 blocks x 448 threads. Block = (32 q-rows) x (7 heads of one kvh).
// Each wave: two 16-row q groups; kf/vf b128 reads feed 2 MFMAs each.
// Single-buffered K/V; stageV(kt) before QK^T, E=vmcnt+barrier, stageK(kt+1)
// before PV, G=vmcnt+barrier. XOR-swizzled K/V slots.
// R12 softmax: TRUE T13 — per-lane partial max + __all gate (no DS ops);
// shfl-max chain + rescale only on the rare exact path. Scores arrive
// pre-scaled (exp2 domain). l_i per-lane partials, epilogue-reduced.
// launch_bounds (448,2): VGPR cap 256 — DO NOT tighten.
__global__ __launch_bounds__(448, 2)
void attn_kernel(const _Float16* __restrict__ Q,   // [B*S][NH*128] rope'd, pre-scaled
                 const _Float16* __restrict__ Kh,  // [B*S][NKV*128] rope'd
                 const _Float16* __restrict__ Vt,  // [B][NKV][128][S]
                 _Float16* __restrict__ Oh) {      // [B*S][NH*128]
  constexpr int S = 2048, D = 128, NH = 28, NKV = 4;
  const int id = blockIdx.x;
  const int qt = 63 - (id >> 3);           // 32-row q tile, longest first
  const int b = (id >> 2) & 1, kvh = id & 3;
  const int tid = threadIdx.x, lane = tid & 63, wave = tid >> 6;  // wave 0..6
  const int h = kvh * 7 + wave;            // this wave's query head
  const int q0 = qt * 32;
  const int row_f = lane & 15, kg = lane >> 4, kg8 = (lane >> 4) * 8;
  const int kgx = kg8 ^ (((row_f >> 1) & 3) << 3);  // swizzled fragment column

  __shared__ _Float16 Ks[4][64][32];   // [d_chunk][key][32 d] = 16 KB
  __shared__ _Float16 Vs[2][128][32];  // [key_chunk][d][32 keys] = 16 KB
  __shared__ _Float16 Ps[7][32][72];   // per-wave P^T scratch (2 groups)

  // load Q fragments for both 16-row groups (A-operand layout)
  h8 qf0[4], qf1[4];
  {
    const _Float16* qr0 = Q + ((size_t)(b * S + q0 + row_f) * NH + h) * D;
    const _Float16* qr1 = Q + ((size_t)(b * S + q0 + 16 + row_f) * NH + h) * D;
#pragma unroll
    for (int ks = 0; ks < 4; ++ks) {
      qf0[ks] = *(const h8*)(qr0 + ks * 32 + kg8);
      qf1[ks] = *(const h8*)(qr1 + ks * 32 + kg8);
    }
  }
  f4 o_acc0[8] = {}, o_acc1[8] = {};
  float m_i0[4] = {-1e30f, -1e30f, -1e30f, -1e30f};
  float m_i1[4] = {-1e30f, -1e30f, -1e30f, -1e30f};
  float l_i0[4] = {0.f, 0.f, 0.f, 0.f};   // per-lane partials
  float l_i1[4] = {0.f, 0.f, 0.f, 0.f};

  const _Float16* kbase = Kh + ((size_t)(b * S) * NKV + kvh) * D;
  const _Float16* vbase = Vt + ((size_t)(b * NKV + kvh) * D) * S;

  const int kt_max = (q0 + 31) >> 6;  // last 64-key tile (diagonal)

  auto stageK = [&](int kt) {
#pragma unroll
    for (int is = 0; is < 4; ++is) {
      int off = (is * 256 + tid) * 8;
      int chunk = off >> 11;
      int key = (off >> 5) & 63;
      int dl = (off & 31) ^ (((key >> 1) & 3) << 3);
      gload_lds16(kbase + (size_t)(kt * 64 + key) * (NKV * D) + chunk * 32 + dl,
                  &Ks[0][0][0] + off);
    }
  };
  auto stageV = [&](int kt) {
#pragma unroll
    for (int is = 0; is < 4; ++is) {
      int off = (is * 256 + tid) * 8;
      int chunk = off >> 12;
      int d = (off >> 5) & 127;
      int kl = (off & 31) ^ (((d >> 1) & 3) << 3);
      gload_lds16(vbase + (size_t)d * S + kt * 64 + chunk * 32 + kl,
                  &Vs[0][0][0] + off);
    }
  };

  // softmax for one 16-row group; T13 per-lane gate (no DS in common case)
  auto softmax_g = [&](f4* s_acc, float* m_i, float* l_i, f4* o_acc,
                       int goff, bool diag, int kt) {
    float sv[4][4];
#pragma unroll
    for (int nt = 0; nt < 4; ++nt) {
#pragma unroll
      for (int r = 0; r < 4; ++r) {
        float v = s_acc[nt][r];   // already scaled (rope pre-scale)
        if (diag) {
          int key = kt * 64 + nt * 16 + row_f;
          int row = q0 + goff + kg * 4 + r;
          if (key > row) v = -1e30f;
        }
        sv[nt][r] = v;
      }
    }
    float pmax[4];
    bool ok = true;
#pragma unroll
    for (int r = 0; r < 4; ++r) {
      pmax[r] = fmaxf(fmaxf(sv[0][r], sv[1][r]), fmaxf(sv[2][r], sv[3][r]));
      ok = ok && (pmax[r] <= m_i[r] + 8.0f);
    }
    if (!__all(ok)) {
#pragma unroll
      for (int r = 0; r < 4; ++r) {
        float mx = pmax[r];
#pragma unroll
        for (int off = 8; off >= 1; off >>= 1)
          mx = fmaxf(mx, __shfl_xor(mx, off, 64));
        float mn = fmaxf(m_i[r], mx);
        float alpha = exp2f(m_i[r] - mn);
        m_i[r] = mn;
        l_i[r] *= alpha;
#pragma unroll
        for (int dt = 0; dt < 8; ++dt) o_acc[dt][r] *= alpha;
      }
    }
#pragma unroll
    for (int r = 0; r < 4; ++r) {
      float ls = 0.f;
#pragma unroll
      for (int nt = 0; nt < 4; ++nt) {
        float p = exp2f(sv[nt][r] - m_i[r]);   // bounded by 2^8 when gated
        sv[nt][r] = p;
        ls += p;
      }
      l_i[r] += ls;
    }
#pragma unroll
    for (int nt = 0; nt < 4; ++nt)
#pragma unroll
      for (int r = 0; r < 4; ++r)
        Ps[wave][goff + kg * 4 + r][nt * 16 + row_f] = (_Float16)sv[nt][r];
  };

  // prologue: K(0) resident before first QK^T
  if (tid < 256) stageK(0);
  asm volatile("s_waitcnt vmcnt(0)" ::: "memory");
  __builtin_amdgcn_s_barrier();
  __builtin_amdgcn_sched_barrier(0);

  for (int kt = 0; kt <= kt_max; ++kt) {
    if (tid < 256) stageV(kt);
    __builtin_amdgcn_sched_barrier(0);

    // S = Q K^T  (32 q x 64 keys per wave; each kf feeds 2 MFMAs)
    f4 s0[4] = {}, s1[4] = {};
    __builtin_amdgcn_s_setprio(1);
#pragma unroll
    for (int ks = 0; ks < 4; ++ks) {
#pragma unroll
      for (int nt = 0; nt < 4; ++nt) {
        h8 kf = *(const h8*)&Ks[ks][nt * 16 + row_f][kgx];
        s0[nt] = __builtin_amdgcn_mfma_f32_16x16x32_f16(qf0[ks], kf, s0[nt], 0, 0, 0);
        s1[nt] = __builtin_amdgcn_mfma_f32_16x16x32_f16(qf1[ks], kf, s1[nt], 0, 0, 0);
      }
    }
    __builtin_amdgcn_s_setprio(0);

    const bool diag = (kt == kt_max);
    softmax_g(s0, m_i0, l_i0, o_acc0, 0, diag, kt);
    softmax_g(s1, m_i1, l_i1, o_acc1, 16, diag, kt);

    // E: V(kt) landed; all waves done reading Ks -> safe to overwrite.
    __builtin_amdgcn_sched_barrier(0);
    asm volatile("s_waitcnt vmcnt(0)" ::: "memory");
    __builtin_amdgcn_s_barrier();
    __builtin_amdgcn_sched_barrier(0);

    if (kt < kt_max && tid < 256) stageK(kt + 1);
    __builtin_amdgcn_sched_barrier(0);

    // O += P V  (each vf feeds 2 MFMAs)
    __builtin_amdgcn_s_setprio(1);
#pragma unroll
    for (int kv = 0; kv < 2; ++kv) {
      h8 pf0 = *(const h8*)&Ps[wave][row_f][kv * 32 + kg8];
      h8 pf1 = *(const h8*)&Ps[wave][16 + row_f][kv * 32 + kg8];
#pragma unroll
      for (int dt = 0; dt < 8; ++dt) {
        h8 vf = *(const h8*)&Vs[kv][dt * 16 + row_f][kgx];
        o_acc0[dt] = __builtin_amdgcn_mfma_f32_16x16x32_f16(pf0, vf, o_acc0[dt], 0, 0, 0);
        o_acc1[dt] = __builtin_amdgcn_mfma_f32_16x16x32_f16(pf1, vf, o_acc1[dt], 0, 0, 0);
      }
    }
    __builtin_amdgcn_s_setprio(0);

    // G: K(kt+1) landed; all waves done reading Vs -> next stageV safe.
    __builtin_amdgcn_sched_barrier(0);
    asm volatile("s_waitcnt vmcnt(0)" ::: "memory");
    __builtin_amdgcn_s_barrier();
    __builtin_amdgcn_sched_barrier(0);
  }

  // epilogue: reduce l across the 16-lane row group, O /= l, store
  float inv_l0[4], inv_l1[4];
#pragma unroll
  for (int r = 0; r < 4; ++r) {
    float ls0 = l_i0[r], ls1 = l_i1[r];
#pragma unroll
    for (int off = 8; off >= 1; off >>= 1) {
      ls0 += __shfl_xor(ls0, off, 64);
      ls1 += __shfl_xor(ls1, off, 64);
    }
    inv_l0[r] = 1.0f / ls0;
    inv_l1[r] = 1.0f / ls1;
  }
#pragma unroll
  for (int dt = 0; dt < 8; ++dt) {
#pragma unroll
    for (int r = 0; r < 4; ++r) {
      const int tok0 = b * S + q0 + kg * 4 + r;
      const int d = dt * 16 + row_f;
      Oh[((size_t)tok0 * NH + h) * D + d] = (_Float16)(o_acc0[dt][r] * inv_l0[r]);
      Oh[((size_t)(tok0 + 16) * NH + h) * D + d] = (_Float16)(o_acc1[dt][r] * inv_l1[r]);
    }
  }
}

// ---------------------------------------------------------------------------
extern "C" void kernel_launch(void* const* d_in, const int* in_sizes, int n_in,
                              void* d_out, int out_size, void* d_ws, size_t ws_size,
                              hipStream_t stream) {
  const float* hidden    = (const float*)d_in[0];
  const int*   positions = (const int*)d_in[1];
  const float* Wqkv      = (const float*)d_in[2];
  const float* bqkv      = (const float*)d_in[3];
  const float* Wo        = (const float*)d_in[4];
  float* out = (float*)d_out;

  // workspace layout (bytes)
  char* ws = (char*)d_ws;
  _Float16* hs_h  = (_Float16*)(ws);              // 4096x3584 fp16 (later reused as attn out)
  _Float16* Wt    = (_Float16*)(ws + 29360128);   // max 4608x3584 fp16 (Wqkv^T then Wo^T)
  _Float16* qkv_h = (_Float16*)(ws + 62390272);   // 4096x4608 fp16
  _Float16* q_h   = (_Float16*)(ws + 100139008);  // 4096x3584 fp16
  _Float16* k_h   = (_Float16*)(ws + 129499136);  // 4096x512 fp16
  _Float16* vt_h  = (_Float16*)(ws + 133693440);  // 2x4x128x2048 fp16
  // total 137,887,744 bytes

  // 1. [fused] hidden fp32->fp16 + Wqkv^T  (14336 + 144*112 = 30464 blocks)
  fused_pre<<<30464, 256, 0, stream>>>((const float4*)hidden, (h4*)hs_h, Wqkv, Wt);
  // 2. qkv = hidden @ Wqkv + b   (fp16 out) — 128x192 tiles, grid-exact 768
  gemm_wide<<<dim3(24, 32), 256, 0, stream>>>(hs_h, Wt, bqkv, qkv_h, 4096, 4608, 3584);
  // 3. [fused] rope(Q pre-scaled,K) + vtrans + Wo^T (4096+2048+12544 blocks)
  fused_mid<<<18688, 256, 0, stream>>>(qkv_h, positions, q_h, k_h, vt_h, Wo, Wt);
  // 4. flash attention -> attn fp16 (into hs_h, dead after GEMM1)
  attn_kernel<<<512, 448, 0, stream>>>(q_h, k_h, vt_h, hs_h);
  // 5. out = attn @ Wo   (fp32 out) — 128x128 tiles, 896 blocks = 3.5/CU
  gemm_kernel<<<dim3(28, 32), 256, 0, stream>>>(hs_h, Wt, out, 4096, 3584, 3584);
}